// Round 2
// baseline (237.898 us; speedup 1.0000x reference)
//
#include <hip/hip_runtime.h>
#include <math.h>

typedef _Float16 h8 __attribute__((ext_vector_type(8)));
typedef float    f4 __attribute__((ext_vector_type(4)));

#define NHEADS 6
#define HDIM   32
#define NTOK   512
#define NTAB   43   // rel_idx = qsum - ksum + 21 in [0,42]
#define LOG2E  1.44269504088896340736f

// ---- DPP row_ror butterfly reductions over the 16-lane row (VALU pipe, no LDS) ----
#define DPP_ROR(x, n) __int_as_float(__builtin_amdgcn_update_dpp( \
    0, __float_as_int(x), 0x120 + (n), 0xf, 0xf, false))

__device__ inline float rmax16(float x) {
  x = fmaxf(x, DPP_ROR(x, 1));
  x = fmaxf(x, DPP_ROR(x, 2));
  x = fmaxf(x, DPP_ROR(x, 4));
  x = fmaxf(x, DPP_ROR(x, 8));
  return x;
}
__device__ inline float rsum16(float x) {
  x += DPP_ROR(x, 1);
  x += DPP_ROR(x, 2);
  x += DPP_ROR(x, 4);
  x += DPP_ROR(x, 8);
  return x;
}

// ---------------- tiny dynamic position-bias MLP (43 rows x 3->12->12->12->6) ----
__device__ inline void ln_relu12(const float* x, float* t, const float* g, const float* b) {
  float mu = 0.f;
#pragma unroll
  for (int j = 0; j < 12; j++) mu += x[j];
  mu *= (1.f / 12.f);
  float var = 0.f;
#pragma unroll
  for (int j = 0; j < 12; j++) { float d = x[j] - mu; var += d * d; }
  var *= (1.f / 12.f);
  float inv = rsqrtf(var + 1e-5f);
#pragma unroll
  for (int j = 0; j < 12; j++) {
    float y = (x[j] - mu) * inv * g[j] + b[j];
    t[j] = y > 0.f ? y : 0.f;
  }
}

__device__ inline void mm12(const float* t, float* x, const float* w, const float* c) {
#pragma unroll
  for (int j = 0; j < 12; j++) {
    float acc = c[j];
#pragma unroll
    for (int i = 0; i < 12; i++) acc += t[i] * w[i * 12 + j];
    x[j] = acc;
  }
}

__global__ void pos_mlp_kernel(
    const float* __restrict__ pw, const float* __restrict__ pb,
    const float* __restrict__ g1, const float* __restrict__ b1,
    const float* __restrict__ w1, const float* __restrict__ c1,
    const float* __restrict__ g2, const float* __restrict__ b2,
    const float* __restrict__ w2, const float* __restrict__ c2,
    const float* __restrict__ g3, const float* __restrict__ b3,
    const float* __restrict__ w3, const float* __restrict__ c3,
    float* __restrict__ posb)
{
  const int r = threadIdx.x;
  if (r >= NTAB) return;
  // table row r (< 225 so ih==0): biases = (-7, r/15 - 7, r%15 - 7)
  const float bh = -7.0f;
  const float bw = (float)(r / 15) - 7.0f;
  const float bd = (float)(r % 15) - 7.0f;
  float x[12], t[12];
#pragma unroll
  for (int j = 0; j < 12; j++)
    x[j] = bh * pw[j] + bw * pw[12 + j] + bd * pw[24 + j] + pb[j];
  ln_relu12(x, t, g1, b1); mm12(t, x, w1, c1);
  ln_relu12(x, t, g2, b2); mm12(t, x, w2, c2);
  ln_relu12(x, t, g3, b3);
#pragma unroll
  for (int hd = 0; hd < NHEADS; hd++) {
    float acc = c3[hd];
#pragma unroll
    for (int i = 0; i < 12; i++) acc += t[i] * w3[i * NHEADS + hd];
    posb[r * NHEADS + hd] = acc * LOG2E;   // log2-domain bias
  }
}

// ---------------- flash attention, fp16 MFMA, barrier-free K-loop -----------------
// grid (4, 6, 64); block 256 (4 waves). Wave owns 32 queries (2 tiles of 16).
// K and V fragments loaded straight from global (L2-resident: 64 KB per (b,h)).
// Only LDS use: per-wave P D-layout->A-layout round trip + 43-entry bias table.
__global__ __launch_bounds__(256, 4)
void attn_kernel(const float* __restrict__ qp, const float* __restrict__ kp,
                 const float* __restrict__ vp, const float* __restrict__ posb,
                 float* __restrict__ out)
{
  __shared__ _Float16 Ps[4][16 * 72];  // stride 72 halves: 16B-aligned h8 reads
  __shared__ float posw[NTAB];

  const int tid  = threadIdx.x;
  const int wave = tid >> 6;
  const int lane = tid & 63;
  const int quad = lane >> 4;
  const int l16  = lane & 15;
  const int h    = blockIdx.y;
  const int b    = blockIdx.z;
  const int q0   = blockIdx.x * 128 + wave * 32;
  const long bh_off = ((long)(b * NHEADS + h)) * NTOK * HDIM;
  const float* qb = qp + bh_off;
  const float* kb = kp + bh_off;
  const float* vb = vp + bh_off;

  if (tid < NTAB) posw[tid] = posb[tid * NHEADS + h];
  __syncthreads();  // the only barrier in the kernel

  const float SC = 0.17677669529663687f * LOG2E;  // 32^-0.5 * log2(e)

  // Q fragments (A layout: lane holds Q[m=l16][k=quad*8+j]), pre-scaled
  h8 qf[2];
#pragma unroll
  for (int ti = 0; ti < 2; ti++) {
    const float4* qg = (const float4*)(qb + (q0 + ti * 16 + l16) * HDIM);
    float4 a = qg[quad * 2], c = qg[quad * 2 + 1];
    qf[ti][0] = (_Float16)(a.x * SC); qf[ti][1] = (_Float16)(a.y * SC);
    qf[ti][2] = (_Float16)(a.z * SC); qf[ti][3] = (_Float16)(a.w * SC);
    qf[ti][4] = (_Float16)(c.x * SC); qf[ti][5] = (_Float16)(c.y * SC);
    qf[ti][6] = (_Float16)(c.z * SC); qf[ti][7] = (_Float16)(c.w * SC);
  }

  f4 o[2][2];
  float m_[2][4], l_[2][4];
#pragma unroll
  for (int ti = 0; ti < 2; ti++)
#pragma unroll
    for (int r = 0; r < 4; r++) {
      o[ti][0][r] = 0.f; o[ti][1][r] = 0.f;
      m_[ti][r] = -1e30f; l_[ti][r] = 0.f;
    }

  for (int kc = 0; kc < 8; kc++) {
    const int k0 = kc * 64;

    // ---- K fragments from global (B layout: lane holds K[n=l16-row][k=quad*8+j]) ----
    h8 kf[4];
#pragma unroll
    for (int t = 0; t < 4; t++) {
      const float4* kg = (const float4*)(kb + (k0 + t * 16 + l16) * HDIM);
      float4 a = kg[quad * 2], c = kg[quad * 2 + 1];
      kf[t][0] = (_Float16)a.x; kf[t][1] = (_Float16)a.y;
      kf[t][2] = (_Float16)a.z; kf[t][3] = (_Float16)a.w;
      kf[t][4] = (_Float16)c.x; kf[t][5] = (_Float16)c.y;
      kf[t][6] = (_Float16)c.z; kf[t][7] = (_Float16)c.w;
    }
    // ---- V fragments, transposed access (lane holds V[k=quad*8+j][n=hf*16+l16]) ----
    h8 vf[2][2];
#pragma unroll
    for (int kt = 0; kt < 2; kt++)
#pragma unroll
      for (int hf = 0; hf < 2; hf++) {
        const float* vsrc = vb + (k0 + kt * 32 + quad * 8) * HDIM + hf * 16 + l16;
#pragma unroll
        for (int j = 0; j < 8; j++)
          vf[kt][hf][j] = (_Float16)vsrc[j * HDIM];
      }
    // key digit-sums for bias index
    int ks_[4];
#pragma unroll
    for (int t = 0; t < 4; t++) {
      int kgl = k0 + t * 16 + l16;
      ks_[t] = (kgl >> 6) + ((kgl >> 3) & 7) + (kgl & 7);
    }

#pragma unroll
    for (int ti = 0; ti < 2; ti++) {
      // ---- S = Q@K^T + bias (bias folded into MFMA C operand; log2 domain) ----
      f4 s[4];
#pragma unroll
      for (int t = 0; t < 4; t++) {
        f4 cin;
#pragma unroll
        for (int r = 0; r < 4; r++) {
          int qg_ = q0 + ti * 16 + quad * 4 + r;
          int qs21 = (qg_ >> 6) + ((qg_ >> 3) & 7) + (qg_ & 7) + 21;
          cin[r] = posw[qs21 - ks_[t]];
        }
        s[t] = __builtin_amdgcn_mfma_f32_16x16x32_f16(qf[ti], kf[t], cin, 0, 0, 0);
      }
      // ---- online softmax (DPP reductions; state replicated across 16-lane row) ----
      float al[4], rs[4];
#pragma unroll
      for (int r = 0; r < 4; r++) {
        float m0 = fmaxf(fmaxf(s[0][r], s[1][r]), fmaxf(s[2][r], s[3][r]));
        m0 = rmax16(m0);
        float mn = fmaxf(m_[ti][r], m0);
        al[r] = __builtin_amdgcn_exp2f(m_[ti][r] - mn);
        m_[ti][r] = mn;
        rs[r] = 0.f;
      }
#pragma unroll
      for (int t = 0; t < 4; t++)
#pragma unroll
        for (int r = 0; r < 4; r++) {
          float p = __builtin_amdgcn_exp2f(s[t][r] - m_[ti][r]);
          rs[r] += p;
          Ps[wave][(quad * 4 + r) * 72 + t * 16 + l16] = (_Float16)p;
        }
#pragma unroll
      for (int r = 0; r < 4; r++) {
        rs[r] = rsum16(rs[r]);
        l_[ti][r] = l_[ti][r] * al[r] + rs[r];
        o[ti][0][r] *= al[r];
        o[ti][1][r] *= al[r];
      }
      // ---- O += P@V : P re-read in A layout (same wave, no barrier needed) ----
#pragma unroll
      for (int kt = 0; kt < 2; kt++) {
        h8 pf = *(const h8*)&Ps[wave][l16 * 72 + kt * 32 + quad * 8];
        o[ti][0] = __builtin_amdgcn_mfma_f32_16x16x32_f16(pf, vf[kt][0], o[ti][0], 0, 0, 0);
        o[ti][1] = __builtin_amdgcn_mfma_f32_16x16x32_f16(pf, vf[kt][1], o[ti][1], 0, 0, 0);
      }
    }
  }

  // ---- epilogue ----
#pragma unroll
  for (int ti = 0; ti < 2; ti++)
#pragma unroll
    for (int r = 0; r < 4; r++) {
      float inv = 1.f / l_[ti][r];
      float* orow = out + bh_off + (long)(q0 + ti * 16 + quad * 4 + r) * HDIM;
      orow[l16]      = o[ti][0][r] * inv;
      orow[16 + l16] = o[ti][1][r] * inv;
    }
}

extern "C" void kernel_launch(void* const* d_in, const int* in_sizes, int n_in,
                              void* d_out, int out_size, void* d_ws, size_t ws_size,
                              hipStream_t stream) {
  (void)in_sizes; (void)n_in; (void)out_size; (void)ws_size;
  const float* q  = (const float*)d_in[0];
  const float* k  = (const float*)d_in[1];
  const float* v  = (const float*)d_in[2];
  // d_in[3..5] = h,w,d scalars (always 8; hard-coded)
  const float* pw  = (const float*)d_in[6];
  const float* pb  = (const float*)d_in[7];
  const float* g1  = (const float*)d_in[8];
  const float* b1  = (const float*)d_in[9];
  const float* w1  = (const float*)d_in[10];
  const float* c1  = (const float*)d_in[11];
  const float* g2  = (const float*)d_in[12];
  const float* b2  = (const float*)d_in[13];
  const float* w2  = (const float*)d_in[14];
  const float* c2  = (const float*)d_in[15];
  const float* g3  = (const float*)d_in[16];
  const float* b3  = (const float*)d_in[17];
  const float* w3  = (const float*)d_in[18];
  const float* c3  = (const float*)d_in[19];
  float* posb = (float*)d_ws;          // 43*6 floats
  float* outp = (float*)d_out;

  pos_mlp_kernel<<<1, 64, 0, stream>>>(pw, pb, g1, b1, w1, c1, g2, b2, w2, c2,
                                       g3, b3, w3, c3, posb);
  attn_kernel<<<dim3(4, NHEADS, 64), 256, 0, stream>>>(q, k, v, posb, outp);
}

// Round 3
// 213.486 us; speedup vs baseline: 1.1144x; 1.1144x over previous
//
#include <hip/hip_runtime.h>
#include <math.h>

typedef _Float16 h8 __attribute__((ext_vector_type(8)));
typedef float    f4 __attribute__((ext_vector_type(4)));

#define NHEADS 6
#define HDIM   32
#define NTOK   512
#define NTAB   43   // rel_idx = qsum - ksum + 21 in [0,42]
#define LOG2E  1.44269504088896340736f
#define VSTR   520  // Vt row stride in halves (512+8): conflict-free b128 reads

// ---- DPP row_ror butterfly reductions over the 16-lane row (VALU pipe, no LDS) ----
#define DPP_ROR(x, n) __int_as_float(__builtin_amdgcn_update_dpp( \
    0, __float_as_int(x), 0x120 + (n), 0xf, 0xf, false))

__device__ inline float rmax16(float x) {
  x = fmaxf(x, DPP_ROR(x, 1));
  x = fmaxf(x, DPP_ROR(x, 2));
  x = fmaxf(x, DPP_ROR(x, 4));
  x = fmaxf(x, DPP_ROR(x, 8));
  return x;
}
__device__ inline float rsum16(float x) {
  x += DPP_ROR(x, 1);
  x += DPP_ROR(x, 2);
  x += DPP_ROR(x, 4);
  x += DPP_ROR(x, 8);
  return x;
}

__device__ inline int ds3(int x) {  // digit sum base-8, 3 digits
  return (x >> 6) + ((x >> 3) & 7) + (x & 7);
}

// ---------------- tiny MLP helpers (43 rows x 3->12->12->12->6) -------------------
__device__ inline void ln_relu12(const float* x, float* t, const float* g, const float* b) {
  float mu = 0.f;
#pragma unroll
  for (int j = 0; j < 12; j++) mu += x[j];
  mu *= (1.f / 12.f);
  float var = 0.f;
#pragma unroll
  for (int j = 0; j < 12; j++) { float d = x[j] - mu; var += d * d; }
  var *= (1.f / 12.f);
  float inv = rsqrtf(var + 1e-5f);
#pragma unroll
  for (int j = 0; j < 12; j++) {
    float y = (x[j] - mu) * inv * g[j] + b[j];
    t[j] = y > 0.f ? y : 0.f;
  }
}

__device__ inline void mm12(const float* t, float* x, const float* w, const float* c) {
#pragma unroll
  for (int j = 0; j < 12; j++) {
    float acc = c[j];
#pragma unroll
    for (int i = 0; i < 12; i++) acc += t[i] * w[i * 12 + j];
    x[j] = acc;
  }
}

// ---------------- fused flash attention ------------------------------------------
// grid (4, 6, 64); block 256 (4 waves). Wave owns 32 queries (2 tiles of 16).
// V staged (transposed fp16) to LDS once; K-frags direct from global (L2-hot);
// bias via one b128 gather per tile (overlapping-float4 table); pos-MLP fused.
__global__ __launch_bounds__(256, 3)
void attn_kernel(const float* __restrict__ qp, const float* __restrict__ kp,
                 const float* __restrict__ vp, float* __restrict__ out,
                 const float* __restrict__ pw, const float* __restrict__ pb,
                 const float* __restrict__ g1, const float* __restrict__ b1,
                 const float* __restrict__ w1, const float* __restrict__ c1,
                 const float* __restrict__ g2, const float* __restrict__ b2,
                 const float* __restrict__ w2, const float* __restrict__ c2,
                 const float* __restrict__ g3, const float* __restrict__ b3,
                 const float* __restrict__ w3, const float* __restrict__ c3)
{
  __shared__ _Float16 Vt[32 * VSTR];   // 33.3 KB  V^T fp16: Vt[c][key]
  __shared__ _Float16 Ps[4][16 * 72];  // 9.2 KB   per-wave P round-trip
  __shared__ f4   posw4[40];           // posw4[b] = (p[b],p[b+1],p[b+2],p[b+3])
  __shared__ float posp[NTAB];

  const int tid  = threadIdx.x;
  const int wave = tid >> 6;
  const int lane = tid & 63;
  const int quad = lane >> 4;
  const int l16  = lane & 15;
  const int h    = blockIdx.y;
  const int b    = blockIdx.z;
  const int q0   = blockIdx.x * 128 + wave * 32;
  const long bh_off = ((long)(b * NHEADS + h)) * NTOK * HDIM;
  const float* qb = qp + bh_off;
  const float* kb = kp + bh_off;
  const float* vb = vp + bh_off;

  // ---- fused position-bias MLP: threads 0..42 compute table row -> head h ----
  if (tid < NTAB) {
    const float bh_ = -7.0f;
    const float bw_ = (float)(tid / 15) - 7.0f;
    const float bd_ = (float)(tid % 15) - 7.0f;
    float x[12], t[12];
#pragma unroll
    for (int j = 0; j < 12; j++)
      x[j] = bh_ * pw[j] + bw_ * pw[12 + j] + bd_ * pw[24 + j] + pb[j];
    ln_relu12(x, t, g1, b1); mm12(t, x, w1, c1);
    ln_relu12(x, t, g2, b2); mm12(t, x, w2, c2);
    ln_relu12(x, t, g3, b3);
    float acc = c3[h];
#pragma unroll
    for (int i = 0; i < 12; i++) acc += t[i] * w3[i * NHEADS + h];
    posp[tid] = acc * LOG2E;   // log2-domain bias
  }
  __syncthreads();
  if (tid < 40) {
    f4 pv = { posp[tid], posp[tid + 1], posp[tid + 2], posp[tid + 3] };
    posw4[tid] = pv;
  }

  // ---- stage V^T to LDS (key-per-lane: conflict-free 2-lane/bank writes) ----
#pragma unroll
  for (int i = 0; i < 16; i++) {
    int idx = i * 256 + tid;          // 0..4095 float4s
    int c4  = idx >> 9;               // uniform within a wave-iteration
    int key = idx & 511;              // consecutive across the 64 lanes
    float4 vv = *(const float4*)(vb + key * HDIM + c4 * 4);
    Vt[(c4 * 4 + 0) * VSTR + key] = (_Float16)vv.x;
    Vt[(c4 * 4 + 1) * VSTR + key] = (_Float16)vv.y;
    Vt[(c4 * 4 + 2) * VSTR + key] = (_Float16)vv.z;
    Vt[(c4 * 4 + 3) * VSTR + key] = (_Float16)vv.w;
  }
  __syncthreads();   // the only barrier covering Vt + posw4

  const float SC = 0.17677669529663687f * LOG2E;  // 32^-0.5 * log2(e)

  // ---- Q fragments (A layout), pre-scaled ----
  h8 qf[2];
#pragma unroll
  for (int ti = 0; ti < 2; ti++) {
    const float4* qg = (const float4*)(qb + (q0 + ti * 16 + l16) * HDIM);
    float4 a = qg[quad * 2], c = qg[quad * 2 + 1];
    qf[ti][0] = (_Float16)(a.x * SC); qf[ti][1] = (_Float16)(a.y * SC);
    qf[ti][2] = (_Float16)(a.z * SC); qf[ti][3] = (_Float16)(a.w * SC);
    qf[ti][4] = (_Float16)(c.x * SC); qf[ti][5] = (_Float16)(c.y * SC);
    qf[ti][6] = (_Float16)(c.z * SC); qf[ti][7] = (_Float16)(c.w * SC);
  }

  // per-tile bias row-base (qsum of row base + 21); per-lane key digit-sum parts
  int qb21[2];
#pragma unroll
  for (int ti = 0; ti < 2; ti++) qb21[ti] = ds3(q0 + ti * 16 + quad * 4) + 21;
  int kst[4];
#pragma unroll
  for (int t = 0; t < 4; t++) kst[t] = t * 2 + (l16 >> 3) + (l16 & 7);

  f4 o[2][2];
  float m_[2][4], l_[2][4];
#pragma unroll
  for (int ti = 0; ti < 2; ti++)
#pragma unroll
    for (int r = 0; r < 4; r++) {
      o[ti][0][r] = 0.f; o[ti][1][r] = 0.f;
      m_[ti][r] = -1e30f; l_[ti][r] = 0.f;
    }

  for (int kc = 0; kc < 8; kc++) {
    const int k0 = kc * 64;

    // ---- K fragments direct from global (coalesced float4, L2-hot) ----
    h8 kf[4];
#pragma unroll
    for (int t = 0; t < 4; t++) {
      const float4* kg = (const float4*)(kb + (k0 + t * 16 + l16) * HDIM);
      float4 a = kg[quad * 2], c = kg[quad * 2 + 1];
      kf[t][0] = (_Float16)a.x; kf[t][1] = (_Float16)a.y;
      kf[t][2] = (_Float16)a.z; kf[t][3] = (_Float16)a.w;
      kf[t][4] = (_Float16)c.x; kf[t][5] = (_Float16)c.y;
      kf[t][6] = (_Float16)c.z; kf[t][7] = (_Float16)c.w;
    }
    // ---- V fragments from LDS (contiguous h8, conflict-free) ----
    h8 vf[2][2];
#pragma unroll
    for (int kt = 0; kt < 2; kt++)
#pragma unroll
      for (int hf = 0; hf < 2; hf++)
        vf[kt][hf] = *(const h8*)&Vt[(hf * 16 + l16) * VSTR + k0 + kt * 32 + quad * 8];

#pragma unroll
    for (int ti = 0; ti < 2; ti++) {
      // ---- S = Q@K^T + bias (one b128 bias gather per tile; log2 domain) ----
      f4 s[4];
#pragma unroll
      for (int t = 0; t < 4; t++) {
        f4 cin = posw4[qb21[ti] - kc - kst[t]];
        s[t] = __builtin_amdgcn_mfma_f32_16x16x32_f16(qf[ti], kf[t], cin, 0, 0, 0);
      }
      // ---- online softmax (DPP reductions, state replicated per 16-lane row) ----
      float al[4], rs[4];
#pragma unroll
      for (int r = 0; r < 4; r++) {
        float m0 = fmaxf(fmaxf(s[0][r], s[1][r]), fmaxf(s[2][r], s[3][r]));
        m0 = rmax16(m0);
        float mn = fmaxf(m_[ti][r], m0);
        al[r] = __builtin_amdgcn_exp2f(m_[ti][r] - mn);
        m_[ti][r] = mn;
        rs[r] = 0.f;
      }
#pragma unroll
      for (int t = 0; t < 4; t++)
#pragma unroll
        for (int r = 0; r < 4; r++) {
          float p = __builtin_amdgcn_exp2f(s[t][r] - m_[ti][r]);
          rs[r] += p;
          Ps[wave][(quad * 4 + r) * 72 + t * 16 + l16] = (_Float16)p;
        }
#pragma unroll
      for (int r = 0; r < 4; r++) {
        rs[r] = rsum16(rs[r]);
        l_[ti][r] = l_[ti][r] * al[r] + rs[r];
        o[ti][0][r] *= al[r];
        o[ti][1][r] *= al[r];
      }
      // ---- O += P@V (P round-trip within the wave; no barrier) ----
#pragma unroll
      for (int kt = 0; kt < 2; kt++) {
        h8 pf = *(const h8*)&Ps[wave][l16 * 72 + kt * 32 + quad * 8];
        o[ti][0] = __builtin_amdgcn_mfma_f32_16x16x32_f16(pf, vf[kt][0], o[ti][0], 0, 0, 0);
        o[ti][1] = __builtin_amdgcn_mfma_f32_16x16x32_f16(pf, vf[kt][1], o[ti][1], 0, 0, 0);
      }
    }
  }

  // ---- epilogue ----
#pragma unroll
  for (int ti = 0; ti < 2; ti++)
#pragma unroll
    for (int r = 0; r < 4; r++) {
      float inv = 1.f / l_[ti][r];
      float* orow = out + bh_off + (long)(q0 + ti * 16 + quad * 4 + r) * HDIM;
      orow[l16]      = o[ti][0][r] * inv;
      orow[16 + l16] = o[ti][1][r] * inv;
    }
}

extern "C" void kernel_launch(void* const* d_in, const int* in_sizes, int n_in,
                              void* d_out, int out_size, void* d_ws, size_t ws_size,
                              hipStream_t stream) {
  (void)in_sizes; (void)n_in; (void)out_size; (void)d_ws; (void)ws_size;
  const float* q  = (const float*)d_in[0];
  const float* k  = (const float*)d_in[1];
  const float* v  = (const float*)d_in[2];
  // d_in[3..5] = h,w,d scalars (always 8; hard-coded)
  const float* pw  = (const float*)d_in[6];
  const float* pb  = (const float*)d_in[7];
  const float* g1  = (const float*)d_in[8];
  const float* b1  = (const float*)d_in[9];
  const float* w1  = (const float*)d_in[10];
  const float* c1  = (const float*)d_in[11];
  const float* g2  = (const float*)d_in[12];
  const float* b2  = (const float*)d_in[13];
  const float* w2  = (const float*)d_in[14];
  const float* c2  = (const float*)d_in[15];
  const float* g3  = (const float*)d_in[16];
  const float* b3  = (const float*)d_in[17];
  const float* w3  = (const float*)d_in[18];
  const float* c3  = (const float*)d_in[19];
  float* outp = (float*)d_out;

  attn_kernel<<<dim3(4, NHEADS, 64), 256, 0, stream>>>(
      q, k, v, outp, pw, pb, g1, b1, w1, c1, g2, b2, w2, c2, g3, b3, w3, c3);
}